// Round 17
// baseline (4080.888 us; speedup 1.0000x reference)
//
#include <hip/hip_runtime.h>

// ---------------- types / helpers ----------------
typedef __attribute__((ext_vector_type(8))) short bf16x8;
typedef __attribute__((ext_vector_type(4))) float f32x4;

#define MFMA(a, b, c) __builtin_amdgcn_mfma_f32_16x16x32_bf16((a), (b), (c), 0, 0, 0)

__device__ inline short f2bf(float f) {
  unsigned u = __builtin_bit_cast(unsigned, f);
  u += 0x7fffu + ((u >> 16) & 1u);   // round-to-nearest-even
  return (short)(u >> 16);
}
__device__ inline float bf2f(short s) {
  unsigned u = ((unsigned)(unsigned short)s) << 16;
  return __builtin_bit_cast(float, u);
}
__device__ inline float sigm(float x) { return 1.f / (1.f + expf(-x)); }

#define VM_DRAIN() asm volatile("s_waitcnt vmcnt(0)" ::: "memory")

// 8 L3-coherent 16B loads + drain in ONE asm statement (legacy fallback path).
__device__ __forceinline__ void sc_load8(const char* g0, const char* l0,
                                         bf16x8* rg, bf16x8* rl) {
  asm volatile(
      "global_load_dwordx4 %0, %8, off sc0 sc1\n\t"
      "global_load_dwordx4 %1, %8, off offset:1024 sc0 sc1\n\t"
      "global_load_dwordx4 %2, %8, off offset:2048 sc0 sc1\n\t"
      "global_load_dwordx4 %3, %8, off offset:3072 sc0 sc1\n\t"
      "global_load_dwordx4 %4, %9, off sc0 sc1\n\t"
      "global_load_dwordx4 %5, %9, off offset:1024 sc0 sc1\n\t"
      "global_load_dwordx4 %6, %9, off offset:2048 sc0 sc1\n\t"
      "global_load_dwordx4 %7, %9, off offset:3072 sc0 sc1\n\t"
      "s_waitcnt vmcnt(0)"
      : "=&v"(rg[0]), "=&v"(rg[1]), "=&v"(rg[2]), "=&v"(rg[3]),
        "=&v"(rl[0]), "=&v"(rl[1]), "=&v"(rl[2]), "=&v"(rl[3])
      : "v"(g0), "v"(l0)
      : "memory");
}

// R7-proven system-scope state store.
__device__ __forceinline__ void store_short_sys(short* p, short v) {
  int vi = (int)(unsigned short)v;
  asm volatile("global_store_short %0, %1, off sc0 sc1" :: "v"(p), "v"(vi) : "memory");
}

// ---------------- sizes ----------------
#define B_SZ 1024
#define T_SZ 100

// ws layout (bytes)
#define O_GFK   0u
#define O_GFRK  (O_GFK  + 98304u)
#define O_LBK   (O_GFRK + 98304u)
#define O_LBRK  (O_LBK  + 131072u)
#define O_G2    (O_LBRK + 131072u)
#define O_L2    (O_G2   + 2359296u)
#define O_X     (O_L2   + 4194304u)     // [B][T][128] bf16
#define O_X1    (O_X    + 26214400u)    // [B][T][256] bf16
#define O_HG    (O_X1   + 52428800u)    // legacy 2 x [B][512] bf16
#define O_HL    (O_HG   + 2097152u)     // legacy 2 x [B][512] bf16
#define O_BAR   (O_HL   + 2097152u)     // barrier counters (4 KB)
#define O_MS    (O_BAR  + 2097152u)     // [B][512] f32
#define O_HGH   (O_MS   + 2097152u)     // hist: 101 x 1MB (hg[t], t=-1..99)
#define O_HLH   (O_HGH  + 105906176u)   // hist: 101 x 1MB (hl[t], t=-1..99)
#define WS_NEED (O_HLH + 105906176u)

// ---------------- weight pack: dst[nt][kb][c][v] = W[kb*8+v][nt*16+c] (bf16) ----------------
__global__ void pack_b(const float* __restrict__ s1, int K1,
                       const float* __restrict__ s2, int K1p,
                       int Kp, int N, short* __restrict__ dst) {
  int i = blockIdx.x * 256 + threadIdx.x;
  int total = N * Kp;
  if (i >= total) return;
  int v = i & 7, c = (i >> 3) & 15, r = i >> 7;
  int kb8 = Kp >> 3;
  int kb = r % kb8, nt = r / kb8;
  int k = kb * 8 + v, col = nt * 16 + c;
  float val;
  if (k < K1p) val = (k < K1) ? s1[k * N + col] : 0.f;
  else         val = s2[(k - K1p) * N + col];
  dst[i] = f2bf(val);
}

// ---------------- embedding ----------------
__global__ void embed_k(const int* __restrict__ text, const float* __restrict__ emb,
                        short* __restrict__ x) {
  int i = blockIdx.x * 256 + threadIdx.x;
  if (i >= B_SZ * T_SZ * 128) return;
  int col = i & 127, bt = i >> 7;
  float v = 0.f;
  if (col < 100) v = emb[text[bt] * 100 + col];
  x[i] = f2bf(v);
}

// ---------------- layer 1 (R7-proven): GRU(fwd)+LSTM(bwd), H=128; rk LDS-resident ----------
__global__ __launch_bounds__(512) void layer1_k(
    const short* __restrict__ x, const short* __restrict__ gfk,
    const short* __restrict__ gfrk, const float* __restrict__ gfb,
    const short* __restrict__ lbk, const short* __restrict__ lbrk,
    const float* __restrict__ lbb, short* __restrict__ x1) {
  __shared__ __attribute__((aligned(16))) short rkl[65536];
  __shared__ __attribute__((aligned(16))) short xst[16 * 136];
  __shared__ __attribute__((aligned(16))) short hst[16 * 136];
  const int wgid = blockIdx.x;
  const bool gru = wgid < 64;
  const int b0 = (gru ? wgid : wgid - 64) * 16;
  const int tid = threadIdx.x, lane = tid & 63, w = tid >> 6;
  const int c = lane & 15, g = lane >> 4;
  const int NS = gru ? 3 : 4;

  for (int i = tid; i < 16 * 136; i += 512) hst[i] = 0;

  const bf16x8* kp = (const bf16x8*)(gru ? gfk : lbk);
  const bf16x8* rpg = (const bf16x8*)(gru ? gfrk : lbrk);
  {
    bf16x8* rl8 = (bf16x8*)rkl;
    int n8 = gru ? 6144 : 8192;
    for (int i = tid; i < n8; i += 512) rl8[i] = rpg[i];
  }
  const bf16x8* rp = (const bf16x8*)rkl;

  bf16x8 kf[4][4];
  #pragma unroll
  for (int s = 0; s < 4; ++s)
    if (s < NS)
      #pragma unroll
      for (int ks = 0; ks < 4; ++ks)
        kf[s][ks] = kp[((s * 8 + w) * 16 + 4 * ks + g) * 16 + c];

  const int col = w * 16 + c;
  float bz = 0, br_ = 0, bxh = 0, brh = 0, bi_ = 0, bf_ = 0, bc_ = 0, bo_ = 0;
  if (gru) {
    bz  = gfb[col]       + gfb[384 + col];
    br_ = gfb[128 + col] + gfb[512 + col];
    bxh = gfb[256 + col];
    brh = gfb[640 + col];
  } else {
    bi_ = lbb[col]; bf_ = lbb[128 + col]; bc_ = lbb[256 + col]; bo_ = lbb[384 + col];
  }

  float hreg[4] = {0.f, 0.f, 0.f, 0.f};
  float cst[4]  = {0.f, 0.f, 0.f, 0.f};

  for (int tt = 0; tt < T_SZ; ++tt) {
    const int t = gru ? tt : (T_SZ - 1 - tt);
    __syncthreads();
    if (tid < 256) {
      int row = tid >> 4, ch = tid & 15;
      *(bf16x8*)&xst[row * 136 + ch * 8] =
          *(const bf16x8*)&x[((b0 + row) * T_SZ + t) * 128 + ch * 8];
    }
    __syncthreads();

    f32x4 acc[4];
    #pragma unroll
    for (int s = 0; s < 4; ++s) acc[s] = (f32x4){0.f, 0.f, 0.f, 0.f};

    bf16x8 ax[4], ah[4];
    #pragma unroll
    for (int ks = 0; ks < 4; ++ks) {
      ax[ks] = *(const bf16x8*)&xst[c * 136 + ks * 32 + g * 8];
      ah[ks] = *(const bf16x8*)&hst[c * 136 + ks * 32 + g * 8];
    }
    #pragma unroll
    for (int s = 0; s < 4; ++s) {
      if (s < NS) {
        int dst = (gru && s == 2) ? 3 : s;
        #pragma unroll
        for (int ks = 0; ks < 4; ++ks) {
          acc[s] = MFMA(ax[ks], kf[s][ks], acc[s]);
          bf16x8 bh = rp[((s * 8 + w) * 16 + 4 * ks + g) * 16 + c];
          acc[dst] = MFMA(ah[ks], bh, acc[dst]);
        }
      }
    }
    __syncthreads();

    if (gru) {
      #pragma unroll
      for (int j = 0; j < 4; ++j) {
        float z  = sigm(acc[0][j] + bz);
        float r  = sigm(acc[1][j] + br_);
        float hh = tanhf(acc[2][j] + bxh + r * (acc[3][j] + brh));
        float hn = z * hreg[j] + (1.f - z) * hh;
        hreg[j] = hn;
        short hb = f2bf(hn);
        int row = 4 * g + j;
        hst[row * 136 + col] = hb;
        x1[((b0 + row) * T_SZ + t) * 256 + col] = hb;
      }
    } else {
      #pragma unroll
      for (int j = 0; j < 4; ++j) {
        float i_ = acc[0][j] + bi_;
        float f_ = acc[1][j] + bf_;
        float cc = acc[2][j] + bc_;
        float o_ = acc[3][j] + bo_;
        float cn = sigm(f_) * cst[j] + sigm(i_) * tanhf(cc);
        cst[j] = cn;
        float hn = sigm(o_) * tanhf(cn);
        short hb = f2bf(hn);
        int row = 4 * g + j;
        hst[row * 136 + col] = hb;
        x1[((b0 + row) * T_SZ + t) * 256 + 128 + col] = hb;
      }
    }
  }
}

// ---------------- 8-wg group barrier: relaxed agent atomics, no fences ---------------------
__device__ __forceinline__ void gbar8(unsigned* bar, int grp, int gen) {
  VM_DRAIN();
  __syncthreads();
  if (threadIdx.x == 0) {
    unsigned want = (unsigned)(gen + 1);
    unsigned* cnt = bar + grp * 32;
    unsigned* rel = cnt + 16;
    unsigned o = __hip_atomic_fetch_add(cnt, 1u, __ATOMIC_RELAXED, __HIP_MEMORY_SCOPE_AGENT);
    if (o == want * 8u - 1u) {
      __hip_atomic_store(rel, want, __ATOMIC_RELAXED, __HIP_MEMORY_SCOPE_AGENT);
    } else {
      unsigned tries = 0;
      while (__hip_atomic_load(rel, __ATOMIC_RELAXED, __HIP_MEMORY_SCOPE_AGENT) < want) {
        __builtin_amdgcn_s_sleep(2);
        if (++tries > (1u << 22)) break;   // bailout: wrong results instead of hang
      }
    }
  }
  __syncthreads();
}

// ---------------- persistent layer 2: 32 row-groups x 8 col-wgs (halved state traffic) -----
// R14 fused schedule in the proven shell: 256 wgs x 512 thr, 1 wg/CU (128 KB LDS declared),
// hist slabs + sc0sc1 stores + plain cached reads, strided grouping (rowwg = wgid&31).
// Each wg: 32 batch rows x 64 h-cols -> per-step state read 64 KB/wg (was 128 KB), total
// 16 MB/step (was 32). Per step (3 syncs): stage hg+hl (32 KB each) -> sync -> single MFMA
// phase (GRU unit + LSTM unit per wave; x1 A-fragments direct from global) + hold pull ->
// sync -> gate-buffer writes (XFg over hgst, XFl over hlst; 8192 floats each, exact fit) ->
// sync -> both epilogues -> gbar8.
__global__ __launch_bounds__(512, 2) void persist2_k(
    const short* __restrict__ x1, const short* __restrict__ G2p, const float* __restrict__ g2b,
    const short* __restrict__ L2p, const float* __restrict__ l2b,
    short* __restrict__ hg, short* __restrict__ hl,
    short* __restrict__ hgH, short* __restrict__ hlH,
    float* __restrict__ msum, unsigned* __restrict__ bar, int mode) {
  __shared__ __attribute__((aligned(16))) short Asm[65536];   // declare 128 KB -> 1 wg/CU (proven)
  // used: hgst shorts [0,16384) = 32 KB; hlst shorts [16384,32768) = 32 KB
  float* XFg = (float*)Asm;             // 4 slots x 32 rows x 64 = 8192 floats (overlays hgst)
  float* XFl = ((float*)Asm) + 8192;    // 8192 floats (overlays hlst)

  const int wgid = blockIdx.x;
  const int rowwg = wgid & 31, colwg = wgid >> 5;   // strided groups of 8 (R7-style)
  const int b0 = rowwg * 32;
  const int tid = threadIdx.x, w = tid >> 6, lane = tid & 63;
  const int c = lane & 15, g = lane >> 4;
  const int c7 = c & 7;
  const int ehc = lane;                 // col within wg (0..63)
  const int er0 = w * 4;                // rows er0..er0+3 per thread
  const int hcg = colwg * 64 + ehc;     // global h-col (0..511)

  const float bz  = g2b[hcg] + g2b[1536 + hcg];
  const float br_ = g2b[512 + hcg] + g2b[2048 + hcg];
  const float bxh = g2b[1024 + hcg];
  const float brh = g2b[2560 + hcg];
  const float bi_ = l2b[hcg], bf_ = l2b[512 + hcg];
  const float bc_ = l2b[1024 + hcg], bo_ = l2b[1536 + hcg];

  const bf16x8* Gv  = (const bf16x8*)G2p;
  const bf16x8* L2v = (const bf16x8*)L2p;
  const bf16x8* x1v = (const bf16x8*)x1;

  // wave roles: LSTM (gate = w>>1, nt pair = w&1), GRU (slot, nt pair)
  const int lgate = w >> 1, ntp = w & 1;
  const int gslot = (w < 4) ? (w >> 1) : (2 + ((w >> 1) & 1));  // 0=z,1=r,2=xh,3=hh
  const int gbase = (gslot == 0) ? 0 : (gslot == 1) ? 32 : 64;
  const int gks0  = (gslot == 3) ? 8 : 0;             // hh: h-part only
  const int gksN  = (gslot == 2) ? 8 : 24;            // xh: x-part only

  float creg[4] = {0.f, 0.f, 0.f, 0.f};
  float mreg[4] = {0.f, 0.f, 0.f, 0.f};

  for (int k = 0; k <= 100; ++k) {
    const short* hg_rd = mode ? hgH + (size_t)k * 524288
                              : hg + (size_t)((k + 1) & 1) * 524288;   // h_g[k-1]
    const short* hl_rd = mode ? hlH + (size_t)(k >= 1 ? k - 1 : 0) * 524288
                              : hl + (size_t)(k & 1) * 524288;         // h_l[k-2]

    // ---- state loads + stage BOTH slabs (wave w owns rows w*4..w*4+3) ----
    bf16x8 rg[4], rl[4];
    {
      const char* bg = (const char*)hg_rd + (size_t)(b0 + w * 4) * 1024 + (size_t)lane * 16;
      const char* bl = (const char*)hl_rd + (size_t)(b0 + w * 4) * 1024 + (size_t)lane * 16;
      if (mode) {
        #pragma unroll
        for (int q = 0; q < 4; ++q) rg[q] = *(const bf16x8*)(bg + q * 1024);
        #pragma unroll
        for (int q = 0; q < 4; ++q) rl[q] = *(const bf16x8*)(bl + q * 1024);
      } else {
        sc_load8(bg, bl, rg, rl);
      }
    }
    #pragma unroll
    for (int q = 0; q < 4; ++q) {
      int r = w * 4 + q;
      *(bf16x8*)&Asm[r * 512 + ((lane ^ (r & 7)) << 3)] = rg[q];
    }
    #pragma unroll
    for (int q = 0; q < 4; ++q) {
      int r = w * 4 + q;
      *(bf16x8*)&Asm[16384 + r * 512 + ((lane ^ (r & 7)) << 3)] = rl[q];
    }
    __syncthreads();

    // ---- single MFMA phase: GRU unit + LSTM unit per wave ----
    f32x4 ga[2][2], la[2][2];
    #pragma unroll
    for (int ni = 0; ni < 2; ++ni)
      #pragma unroll
      for (int m = 0; m < 2; ++m) {
        ga[ni][m] = (f32x4){0.f, 0.f, 0.f, 0.f};
        la[ni][m] = (f32x4){0.f, 0.f, 0.f, 0.f};
      }

    if (k < 100) {
      for (int ks = gks0; ks < gksN; ++ks) {
        bf16x8 a[2];
        #pragma unroll
        for (int m = 0; m < 2; ++m) {
          if (ks < 8)   // x-part: A-fragment straight from global x1 (lane-local 16B)
            a[m] = x1v[((size_t)(b0 + m * 16 + c) * T_SZ + k) * 32 + ks * 4 + g];
          else          // h-part from hgst
            a[m] = *(const bf16x8*)&Asm[(m * 16 + c) * 512 + ((((ks - 8) * 4 + g) ^ c7) << 3)];
        }
        #pragma unroll
        for (int ni = 0; ni < 2; ++ni) {
          int gnt = gbase + colwg * 4 + ntp * 2 + ni;
          bf16x8 b = Gv[((size_t)gnt * 96 + 4 * ks + g) * 16 + c];
          #pragma unroll
          for (int m = 0; m < 2; ++m) ga[ni][m] = MFMA(a[m], b, ga[ni][m]);
        }
      }
    }
    if (k >= 1) {
      for (int ks = 0; ks < 32; ++ks) {
        bf16x8 a[2];
        #pragma unroll
        for (int m = 0; m < 2; ++m)
          a[m] = (ks < 16)
              ? *(const bf16x8*)&Asm[(m * 16 + c) * 512 + (((ks * 4 + g) ^ c7) << 3)]
              : *(const bf16x8*)&Asm[16384 + (m * 16 + c) * 512 + ((((ks - 16) * 4 + g) ^ c7) << 3)];
        #pragma unroll
        for (int ni = 0; ni < 2; ++ni) {
          int lnt = lgate * 32 + colwg * 4 + ntp * 2 + ni;
          bf16x8 b = L2v[((size_t)lnt * 128 + 4 * ks + g) * 16 + c];
          #pragma unroll
          for (int m = 0; m < 2; ++m) la[ni][m] = MFMA(a[m], b, la[ni][m]);
        }
      }
    }

    // pull h_g[k-1] (hold) before XF buffers overlay hgst
    float hold[4];
    if (k < 100) {
      #pragma unroll
      for (int j = 0; j < 4; ++j) {
        int r = er0 + j;
        hold[j] = bf2f(Asm[r * 512 + (((hcg >> 3) ^ (r & 7)) << 3) + (hcg & 7)]);
      }
    }
    __syncthreads();   // all LDS A reads + hold done -> XF may overlay

    // ---- gate-buffer writes (slot stride = 32*64 = 2048 floats) ----
    if (k < 100) {
      #pragma unroll
      for (int ni = 0; ni < 2; ++ni)
        #pragma unroll
        for (int m = 0; m < 2; ++m)
          #pragma unroll
          for (int j = 0; j < 4; ++j)
            XFg[(gslot * 32 + m * 16 + 4 * g + j) * 64 + (ntp * 2 + ni) * 16 + c] = ga[ni][m][j];
    }
    if (k >= 1) {
      #pragma unroll
      for (int ni = 0; ni < 2; ++ni)
        #pragma unroll
        for (int m = 0; m < 2; ++m)
          #pragma unroll
          for (int j = 0; j < 4; ++j)
            XFl[(lgate * 32 + m * 16 + 4 * g + j) * 64 + (ntp * 2 + ni) * 16 + c] = la[ni][m][j];
    }
    __syncthreads();

    // ---- epilogues ----
    if (k < 100) {
      short* hgw = mode ? hgH + (size_t)(k + 1) * 524288
                        : hg + (size_t)(k & 1) * 524288;
      #pragma unroll
      for (int j = 0; j < 4; ++j) {
        int r = er0 + j;
        int xi = r * 64 + ehc;
        float z  = sigm(XFg[xi] + bz);
        float rr = sigm(XFg[2048 + xi] + br_);
        float hh = tanhf(XFg[4096 + xi] + bxh + rr * (XFg[6144 + xi] + brh));
        float hn = z * hold[j] + (1.f - z) * hh;
        store_short_sys(&hgw[(size_t)(b0 + r) * 512 + hcg], f2bf(hn));
      }
    }
    if (k >= 1) {
      short* hlw = mode ? hlH + (size_t)k * 524288
                        : hl + (size_t)((k + 1) & 1) * 524288;   // h_l[t], t=k-1
      #pragma unroll
      for (int j = 0; j < 4; ++j) {
        int r = er0 + j;
        int xi = r * 64 + ehc;
        float i_ = XFl[xi]        + bi_;
        float f_ = XFl[2048 + xi] + bf_;
        float cc = XFl[4096 + xi] + bc_;
        float o_ = XFl[6144 + xi] + bo_;
        float cn = sigm(f_) * creg[j] + sigm(i_) * tanhf(cc);
        creg[j] = cn;
        float hn = sigm(o_) * tanhf(cn);
        mreg[j] += hn;
        store_short_sys(&hlw[(size_t)(b0 + r) * 512 + hcg], f2bf(hn));
      }
    }

    gbar8(bar, rowwg, k);
  }

  #pragma unroll
  for (int j = 0; j < 4; ++j)
    msum[(size_t)(b0 + er0 + j) * 512 + hcg] = mreg[j];
}

// ---------------- head: mean -> MLP -> softmax/sigmoid ----------------
__global__ __launch_bounds__(256) void head_k(
    const float* __restrict__ msum, const float* __restrict__ upv,
    const float* __restrict__ fc1w, const float* __restrict__ fc1b,
    const float* __restrict__ d1w, const float* __restrict__ d1b,
    const float* __restrict__ d2w, const float* __restrict__ d2b,
    const float* __restrict__ d3w, const float* __restrict__ d3b,
    const float* __restrict__ rw, const float* __restrict__ rb,
    const float* __restrict__ cw, const float* __restrict__ cb,
    float* __restrict__ out) {
  __shared__ float h[1024], o1[64], o2[512], o3[128], lg[8];
  const int b = blockIdx.x, tid = threadIdx.x;
  const float u = upv[b];
  for (int i = tid; i < 512; i += 256) {
    h[i] = msum[b * 512 + i] * 0.01f;
    float v = u * fc1w[i] + fc1b[i];
    h[512 + i] = v > 0.f ? v : 0.f;
  }
  __syncthreads();
  if (tid < 64) {
    float a = d1b[tid];
    for (int i = 0; i < 1024; ++i) a += h[i] * d1w[i * 64 + tid];
    o1[tid] = a > 0.f ? a : 0.f;
  }
  __syncthreads();
  for (int j = tid; j < 512; j += 256) {
    float a = d2b[j];
    for (int i = 0; i < 64; ++i) a += o1[i] * d2w[i * 512 + j];
    o2[j] = a > 0.f ? a : 0.f;
  }
  __syncthreads();
  if (tid < 128) {
    float a = d3b[tid];
    for (int i = 0; i < 512; ++i) a += o2[i] * d3w[i * 128 + tid];
    o3[tid] = a > 0.f ? a : 0.f;
  }
  __syncthreads();
  if (tid < 5) {
    float a = rb[tid];
    for (int i = 0; i < 128; ++i) a += o3[i] * rw[i * 5 + tid];
    lg[tid] = a;
  }
  if (tid == 5) {
    float a = cb[0];
    for (int i = 0; i < 128; ++i) a += o3[i] * cw[i];
    out[5120 + b] = 1.f / (1.f + expf(-a));
  }
  __syncthreads();
  if (tid == 0) {
    float m = lg[0];
    for (int j = 1; j < 5; ++j) m = fmaxf(m, lg[j]);
    float e[5], s = 0.f;
    for (int j = 0; j < 5; ++j) { e[j] = expf(lg[j] - m); s += e[j]; }
    for (int j = 0; j < 5; ++j) out[b * 5 + j] = e[j] / s;
  }
}

// ---------------- launch ----------------
extern "C" void kernel_launch(void* const* d_in, const int* in_sizes, int n_in,
                              void* d_out, int out_size, void* d_ws, size_t ws_size,
                              hipStream_t stream) {
  const int*   text  = (const int*)  d_in[0];
  const float* upv   = (const float*)d_in[1];
  const float* emb   = (const float*)d_in[2];
  const float* gf_k  = (const float*)d_in[3];
  const float* gf_rk = (const float*)d_in[4];
  const float* gf_b  = (const float*)d_in[5];
  const float* lb_k  = (const float*)d_in[6];
  const float* lb_rk = (const float*)d_in[7];
  const float* lb_b  = (const float*)d_in[8];
  const float* g2_k  = (const float*)d_in[9];
  const float* g2_rk = (const float*)d_in[10];
  const float* g2_b  = (const float*)d_in[11];
  const float* l2_k  = (const float*)d_in[12];
  const float* l2_rk = (const float*)d_in[13];
  const float* l2_b  = (const float*)d_in[14];
  const float* fc1_w = (const float*)d_in[15];
  const float* fc1_b = (const float*)d_in[16];
  const float* d1_w  = (const float*)d_in[17];
  const float* d1_b  = (const float*)d_in[18];
  const float* d2_w  = (const float*)d_in[19];
  const float* d2_b  = (const float*)d_in[20];
  const float* d3_w  = (const float*)d_in[21];
  const float* d3_b  = (const float*)d_in[22];
  const float* rat_w = (const float*)d_in[23];
  const float* rat_b = (const float*)d_in[24];
  const float* rec_w = (const float*)d_in[25];
  const float* rec_b = (const float*)d_in[26];

  char* ws = (char*)d_ws;
  short* gfkp  = (short*)(ws + O_GFK);
  short* gfrkp = (short*)(ws + O_GFRK);
  short* lbkp  = (short*)(ws + O_LBK);
  short* lbrkp = (short*)(ws + O_LBRK);
  short* G2p   = (short*)(ws + O_G2);
  short* L2p   = (short*)(ws + O_L2);
  short* xb    = (short*)(ws + O_X);
  short* x1    = (short*)(ws + O_X1);
  short* hg    = (short*)(ws + O_HG);
  short* hl    = (short*)(ws + O_HL);
  unsigned* bar = (unsigned*)(ws + O_BAR);
  float* msum  = (float*)(ws + O_MS);
  short* hgH   = (short*)(ws + O_HGH);
  short* hlH   = (short*)(ws + O_HLH);

  const int mode = (ws_size >= (size_t)WS_NEED) ? 1 : 0;

  pack_b<<<192, 256, 0, stream>>>(gf_k, 100, gf_k, 128, 128, 384, gfkp);
  pack_b<<<192, 256, 0, stream>>>(gf_rk, 128, gf_rk, 128, 128, 384, gfrkp);
  pack_b<<<256, 256, 0, stream>>>(lb_k, 100, lb_k, 128, 128, 512, lbkp);
  pack_b<<<256, 256, 0, stream>>>(lb_rk, 128, lb_rk, 128, 128, 512, lbrkp);
  pack_b<<<4608, 256, 0, stream>>>(g2_k, 256, g2_rk, 256, 768, 1536, G2p);
  pack_b<<<8192, 256, 0, stream>>>(l2_k, 512, l2_rk, 512, 1024, 2048, L2p);

  embed_k<<<51200, 256, 0, stream>>>(text, emb, xb);

  hipMemsetAsync(ws + O_BAR, 0, 4096u, stream);               // barrier counters
  if (mode) {
    hipMemsetAsync(ws + O_HGH, 0, 1048576u, stream);          // hg[-1] = 0
    hipMemsetAsync(ws + O_HLH, 0, 1048576u, stream);          // hl[-1] = 0
  } else {
    hipMemsetAsync(ws + O_HG + 1048576u, 0, 1048576u, stream);
    hipMemsetAsync(ws + O_HL + 1048576u, 0, 1048576u, stream);
  }

  layer1_k<<<128, 512, 0, stream>>>(xb, gfkp, gfrkp, gf_b, lbkp, lbrkp, lb_b, x1);

  {
    const short* x1c = x1; const short* G2c = G2p; const short* L2c = L2p;
    int modec = mode;
    void* kargs[] = {(void*)&x1c, (void*)&G2c, (void*)&g2_b, (void*)&L2c, (void*)&l2_b,
                     (void*)&hg, (void*)&hl, (void*)&hgH, (void*)&hlH,
                     (void*)&msum, (void*)&bar, (void*)&modec};
    hipError_t e = hipLaunchCooperativeKernel((void*)persist2_k, dim3(256), dim3(512),
                                              kargs, 0, stream);
    if (e != hipSuccess) {
      (void)hipGetLastError();  // clear
      persist2_k<<<256, 512, 0, stream>>>(x1c, G2c, g2_b, L2c, l2_b, hg, hl, hgH, hlH,
                                          msum, bar, modec);
    }
  }

  head_k<<<1024, 256, 0, stream>>>(msum, upv, fc1_w, fc1_b, d1_w, d1_b, d2_w, d2_b,
                                   d3_w, d3_b, rat_w, rat_b, rec_w, rec_b,
                                   (float*)d_out);
}

// Round 18
// 2881.714 us; speedup vs baseline: 1.4161x; 1.4161x over previous
//
#include <hip/hip_runtime.h>

// ---------------- types / helpers ----------------
typedef __attribute__((ext_vector_type(8))) short bf16x8;
typedef __attribute__((ext_vector_type(4))) float f32x4;

#define MFMA(a, b, c) __builtin_amdgcn_mfma_f32_16x16x32_bf16((a), (b), (c), 0, 0, 0)

__device__ inline short f2bf(float f) {
  unsigned u = __builtin_bit_cast(unsigned, f);
  u += 0x7fffu + ((u >> 16) & 1u);   // round-to-nearest-even
  return (short)(u >> 16);
}
__device__ inline float bf2f(short s) {
  unsigned u = ((unsigned)(unsigned short)s) << 16;
  return __builtin_bit_cast(float, u);
}
__device__ inline float sigm(float x) { return 1.f / (1.f + expf(-x)); }

#define VM_DRAIN() asm volatile("s_waitcnt vmcnt(0)" ::: "memory")

// 16 L3-coherent 16B loads + drain in ONE asm statement (legacy fallback path).
__device__ __forceinline__ void sc_load16(const char* g0, const char* g1,
                                          const char* l0, const char* l1,
                                          bf16x8* rg, bf16x8* rl) {
  asm volatile(
      "global_load_dwordx4 %0, %16, off sc0 sc1\n\t"
      "global_load_dwordx4 %1, %16, off offset:1024 sc0 sc1\n\t"
      "global_load_dwordx4 %2, %16, off offset:2048 sc0 sc1\n\t"
      "global_load_dwordx4 %3, %16, off offset:3072 sc0 sc1\n\t"
      "global_load_dwordx4 %4, %17, off sc0 sc1\n\t"
      "global_load_dwordx4 %5, %17, off offset:1024 sc0 sc1\n\t"
      "global_load_dwordx4 %6, %17, off offset:2048 sc0 sc1\n\t"
      "global_load_dwordx4 %7, %17, off offset:3072 sc0 sc1\n\t"
      "global_load_dwordx4 %8, %18, off sc0 sc1\n\t"
      "global_load_dwordx4 %9, %18, off offset:1024 sc0 sc1\n\t"
      "global_load_dwordx4 %10, %18, off offset:2048 sc0 sc1\n\t"
      "global_load_dwordx4 %11, %18, off offset:3072 sc0 sc1\n\t"
      "global_load_dwordx4 %12, %19, off sc0 sc1\n\t"
      "global_load_dwordx4 %13, %19, off offset:1024 sc0 sc1\n\t"
      "global_load_dwordx4 %14, %19, off offset:2048 sc0 sc1\n\t"
      "global_load_dwordx4 %15, %19, off offset:3072 sc0 sc1\n\t"
      "s_waitcnt vmcnt(0)"
      : "=&v"(rg[0]), "=&v"(rg[1]), "=&v"(rg[2]), "=&v"(rg[3]),
        "=&v"(rg[4]), "=&v"(rg[5]), "=&v"(rg[6]), "=&v"(rg[7]),
        "=&v"(rl[0]), "=&v"(rl[1]), "=&v"(rl[2]), "=&v"(rl[3]),
        "=&v"(rl[4]), "=&v"(rl[5]), "=&v"(rl[6]), "=&v"(rl[7])
      : "v"(g0), "v"(g1), "v"(l0), "v"(l1)
      : "memory");
}

// R7-proven system-scope state store.
__device__ __forceinline__ void store_short_sys(short* p, short v) {
  int vi = (int)(unsigned short)v;
  asm volatile("global_store_short %0, %1, off sc0 sc1" :: "v"(p), "v"(vi) : "memory");
}

// ---------------- sizes ----------------
#define B_SZ 1024
#define T_SZ 100

// ws layout (bytes)
#define O_GFK   0u
#define O_GFRK  (O_GFK  + 98304u)
#define O_LBK   (O_GFRK + 98304u)
#define O_LBRK  (O_LBK  + 131072u)
#define O_G2    (O_LBRK + 131072u)
#define O_L2    (O_G2   + 2359296u)
#define O_X     (O_L2   + 4194304u)     // [B][T][128] bf16
#define O_X1    (O_X    + 26214400u)    // [B][T][256] bf16
#define O_HG    (O_X1   + 52428800u)    // legacy 2 x [B][512] bf16
#define O_HL    (O_HG   + 2097152u)     // legacy 2 x [B][512] bf16
#define O_BAR   (O_HL   + 2097152u)     // barrier counters (4 KB)
#define O_MS    (O_BAR  + 2097152u)     // [B][512] f32
#define O_HGH   (O_MS   + 2097152u)     // hist: 101 x 1MB (hg[t], t=-1..99)
#define O_HLH   (O_HGH  + 105906176u)   // hist: 101 x 1MB (hl[t], t=-1..99)
#define WS_NEED (O_HLH + 105906176u)

// ---------------- weight pack: dst[nt][kb][c][v] = W[kb*8+v][nt*16+c] (bf16) ----------------
__global__ void pack_b(const float* __restrict__ s1, int K1,
                       const float* __restrict__ s2, int K1p,
                       int Kp, int N, short* __restrict__ dst) {
  int i = blockIdx.x * 256 + threadIdx.x;
  int total = N * Kp;
  if (i >= total) return;
  int v = i & 7, c = (i >> 3) & 15, r = i >> 7;
  int kb8 = Kp >> 3;
  int kb = r % kb8, nt = r / kb8;
  int k = kb * 8 + v, col = nt * 16 + c;
  float val;
  if (k < K1p) val = (k < K1) ? s1[k * N + col] : 0.f;
  else         val = s2[(k - K1p) * N + col];
  dst[i] = f2bf(val);
}

// ---------------- embedding ----------------
__global__ void embed_k(const int* __restrict__ text, const float* __restrict__ emb,
                        short* __restrict__ x) {
  int i = blockIdx.x * 256 + threadIdx.x;
  if (i >= B_SZ * T_SZ * 128) return;
  int col = i & 127, bt = i >> 7;
  float v = 0.f;
  if (col < 100) v = emb[text[bt] * 100 + col];
  x[i] = f2bf(v);
}

// ---------------- layer 1 (R7-proven): GRU(fwd)+LSTM(bwd), H=128; rk LDS-resident ----------
__global__ __launch_bounds__(512) void layer1_k(
    const short* __restrict__ x, const short* __restrict__ gfk,
    const short* __restrict__ gfrk, const float* __restrict__ gfb,
    const short* __restrict__ lbk, const short* __restrict__ lbrk,
    const float* __restrict__ lbb, short* __restrict__ x1) {
  __shared__ __attribute__((aligned(16))) short rkl[65536];
  __shared__ __attribute__((aligned(16))) short xst[16 * 136];
  __shared__ __attribute__((aligned(16))) short hst[16 * 136];
  const int wgid = blockIdx.x;
  const bool gru = wgid < 64;
  const int b0 = (gru ? wgid : wgid - 64) * 16;
  const int tid = threadIdx.x, lane = tid & 63, w = tid >> 6;
  const int c = lane & 15, g = lane >> 4;
  const int NS = gru ? 3 : 4;

  for (int i = tid; i < 16 * 136; i += 512) hst[i] = 0;

  const bf16x8* kp = (const bf16x8*)(gru ? gfk : lbk);
  const bf16x8* rpg = (const bf16x8*)(gru ? gfrk : lbrk);
  {
    bf16x8* rl8 = (bf16x8*)rkl;
    int n8 = gru ? 6144 : 8192;
    for (int i = tid; i < n8; i += 512) rl8[i] = rpg[i];
  }
  const bf16x8* rp = (const bf16x8*)rkl;

  bf16x8 kf[4][4];
  #pragma unroll
  for (int s = 0; s < 4; ++s)
    if (s < NS)
      #pragma unroll
      for (int ks = 0; ks < 4; ++ks)
        kf[s][ks] = kp[((s * 8 + w) * 16 + 4 * ks + g) * 16 + c];

  const int col = w * 16 + c;
  float bz = 0, br_ = 0, bxh = 0, brh = 0, bi_ = 0, bf_ = 0, bc_ = 0, bo_ = 0;
  if (gru) {
    bz  = gfb[col]       + gfb[384 + col];
    br_ = gfb[128 + col] + gfb[512 + col];
    bxh = gfb[256 + col];
    brh = gfb[640 + col];
  } else {
    bi_ = lbb[col]; bf_ = lbb[128 + col]; bc_ = lbb[256 + col]; bo_ = lbb[384 + col];
  }

  float hreg[4] = {0.f, 0.f, 0.f, 0.f};
  float cst[4]  = {0.f, 0.f, 0.f, 0.f};

  for (int tt = 0; tt < T_SZ; ++tt) {
    const int t = gru ? tt : (T_SZ - 1 - tt);
    __syncthreads();
    if (tid < 256) {
      int row = tid >> 4, ch = tid & 15;
      *(bf16x8*)&xst[row * 136 + ch * 8] =
          *(const bf16x8*)&x[((b0 + row) * T_SZ + t) * 128 + ch * 8];
    }
    __syncthreads();

    f32x4 acc[4];
    #pragma unroll
    for (int s = 0; s < 4; ++s) acc[s] = (f32x4){0.f, 0.f, 0.f, 0.f};

    bf16x8 ax[4], ah[4];
    #pragma unroll
    for (int ks = 0; ks < 4; ++ks) {
      ax[ks] = *(const bf16x8*)&xst[c * 136 + ks * 32 + g * 8];
      ah[ks] = *(const bf16x8*)&hst[c * 136 + ks * 32 + g * 8];
    }
    #pragma unroll
    for (int s = 0; s < 4; ++s) {
      if (s < NS) {
        int dst = (gru && s == 2) ? 3 : s;
        #pragma unroll
        for (int ks = 0; ks < 4; ++ks) {
          acc[s] = MFMA(ax[ks], kf[s][ks], acc[s]);
          bf16x8 bh = rp[((s * 8 + w) * 16 + 4 * ks + g) * 16 + c];
          acc[dst] = MFMA(ah[ks], bh, acc[dst]);
        }
      }
    }
    __syncthreads();

    if (gru) {
      #pragma unroll
      for (int j = 0; j < 4; ++j) {
        float z  = sigm(acc[0][j] + bz);
        float r  = sigm(acc[1][j] + br_);
        float hh = tanhf(acc[2][j] + bxh + r * (acc[3][j] + brh));
        float hn = z * hreg[j] + (1.f - z) * hh;
        hreg[j] = hn;
        short hb = f2bf(hn);
        int row = 4 * g + j;
        hst[row * 136 + col] = hb;
        x1[((b0 + row) * T_SZ + t) * 256 + col] = hb;
      }
    } else {
      #pragma unroll
      for (int j = 0; j < 4; ++j) {
        float i_ = acc[0][j] + bi_;
        float f_ = acc[1][j] + bf_;
        float cc = acc[2][j] + bc_;
        float o_ = acc[3][j] + bo_;
        float cn = sigm(f_) * cst[j] + sigm(i_) * tanhf(cc);
        cst[j] = cn;
        float hn = sigm(o_) * tanhf(cn);
        short hb = f2bf(hn);
        int row = 4 * g + j;
        hst[row * 136 + col] = hb;
        x1[((b0 + row) * T_SZ + t) * 256 + 128 + col] = hb;
      }
    }
  }
}

// ---------------- 16-wg group barrier: relaxed agent atomics, no fences --------------------
__device__ __forceinline__ void gbar16(unsigned* bar, int grp, int gen) {
  VM_DRAIN();
  __syncthreads();
  if (threadIdx.x == 0) {
    unsigned want = (unsigned)(gen + 1);
    unsigned* cnt = bar + grp * 32;
    unsigned* rel = cnt + 16;
    unsigned o = __hip_atomic_fetch_add(cnt, 1u, __ATOMIC_RELAXED, __HIP_MEMORY_SCOPE_AGENT);
    if (o == want * 16u - 1u) {
      __hip_atomic_store(rel, want, __ATOMIC_RELAXED, __HIP_MEMORY_SCOPE_AGENT);
    } else {
      unsigned tries = 0;
      while (__hip_atomic_load(rel, __ATOMIC_RELAXED, __HIP_MEMORY_SCOPE_AGENT) < want) {
        __builtin_amdgcn_s_sleep(2);
        if (++tries > (1u << 22)) break;   // bailout: wrong results instead of hang
      }
    }
  }
  __syncthreads();
}

// ---------------- persistent layer 2 (R14/R16 BEST: fused GRU||LSTM phase) -----------------
// R7 shell: 256 wgs x 512 thr, 1 wg/CU, 128 KB LDS, group rowwg = wgid&15, colwg = wgid>>4,
// hist slabs + sc0sc1 stores + plain cached reads, same gbar16.
// Schedule per step (3 syncs): stage hg+hl -> sync -> single MFMA phase (GRU unit + LSTM
// unit per wave, x1 A-fragments direct from global, B-panels streamed from L2) + hold pull
// -> sync -> gate-buffer writes (XFg/XFl overlay LDS) -> sync -> both epilogues -> gbar16.
__global__ __launch_bounds__(512, 2) void persist2_k(
    const short* __restrict__ x1, const short* __restrict__ G2p, const float* __restrict__ g2b,
    const short* __restrict__ L2p, const float* __restrict__ l2b,
    short* __restrict__ hg, short* __restrict__ hl,
    short* __restrict__ hgH, short* __restrict__ hlH,
    float* __restrict__ msum, unsigned* __restrict__ bar, int mode) {
  __shared__ __attribute__((aligned(16))) short Asm[65536];   // A: hgst [0,32768) sh; B: hlst [32768,65536) sh
  float* XFg = (float*)Asm;             // 4 slots x 64 rows x 36 = 9216 floats (overlays hgst)
  float* XFl = ((float*)Asm) + 9216;    // 9216 floats (overlays hgst tail + hlst head)

  const int wgid = blockIdx.x;
  const int rowwg = wgid & 15, colwg = wgid >> 4;   // R7 grouping
  const int b0 = rowwg * 64;
  const int tid = threadIdx.x, w = tid >> 6, lane = tid & 63;
  const int c = lane & 15, g = lane >> 4;
  const int c7 = c & 7;
  const int ehc = lane & 31;
  const int er0 = w * 8 + (lane >> 5) * 4;
  const int hcg = colwg * 32 + ehc;

  const float bz  = g2b[hcg] + g2b[1536 + hcg];
  const float br_ = g2b[512 + hcg] + g2b[2048 + hcg];
  const float bxh = g2b[1024 + hcg];
  const float brh = g2b[2560 + hcg];
  const float bi_ = l2b[hcg], bf_ = l2b[512 + hcg];
  const float bc_ = l2b[1024 + hcg], bo_ = l2b[1536 + hcg];

  const bf16x8* Gv  = (const bf16x8*)G2p;
  const bf16x8* L2v = (const bf16x8*)L2p;
  const bf16x8* x1v = (const bf16x8*)x1;

  // wave roles: LSTM unit (all 8 waves), GRU unit (all 8 waves)
  const int lgate = w >> 1, ln = w & 1;               // LSTM gate, nt half
  const int lntg  = lgate * 32 + colwg * 2 + ln;
  const int gslot = (w < 4) ? (w >> 1) : (2 + ((w >> 1) & 1));  // 0=z,1=r,2=xh,3=hh
  const int gnt   = w & 1;
  const int gbase = (gslot == 0) ? 0 : (gslot == 1) ? 32 : 64;
  const int gntg  = gbase + colwg * 2 + gnt;
  const int gks0  = (gslot == 3) ? 8 : 0;             // hh: h-part only
  const int gksN  = (gslot == 2) ? 8 : 24;            // xh: x-part only

  float creg[4] = {0.f, 0.f, 0.f, 0.f};
  float mreg[4] = {0.f, 0.f, 0.f, 0.f};

  for (int k = 0; k <= 100; ++k) {
    const short* hg_rd = mode ? hgH + (size_t)k * 524288
                              : hg + (size_t)((k + 1) & 1) * 524288;   // h_g[k-1]
    const short* hl_rd = mode ? hlH + (size_t)(k >= 1 ? k - 1 : 0) * 524288
                              : hl + (size_t)(k & 1) * 524288;         // h_l[k-2]

    // ---- state loads + stage BOTH slabs (wave w owns rows w*8..w*8+7) ----
    bf16x8 rg[8], rl[8];
    {
      const char* bg = (const char*)hg_rd + (size_t)(b0 + w * 8) * 1024 + (size_t)lane * 16;
      const char* bl = (const char*)hl_rd + (size_t)(b0 + w * 8) * 1024 + (size_t)lane * 16;
      if (mode) {
        #pragma unroll
        for (int q = 0; q < 8; ++q) rg[q] = *(const bf16x8*)(bg + q * 1024);
        #pragma unroll
        for (int q = 0; q < 8; ++q) rl[q] = *(const bf16x8*)(bl + q * 1024);
      } else {
        sc_load16(bg, bg + 4096, bl, bl + 4096, rg, rl);
      }
    }
    #pragma unroll
    for (int q = 0; q < 8; ++q)
      *(bf16x8*)&Asm[(w * 8 + q) * 512 + ((lane ^ q) << 3)] = rg[q];
    #pragma unroll
    for (int q = 0; q < 8; ++q)
      *(bf16x8*)&Asm[32768 + (w * 8 + q) * 512 + ((lane ^ q) << 3)] = rl[q];
    __syncthreads();

    // ---- single MFMA phase: GRU unit + LSTM unit per wave ----
    f32x4 ga[4], la[4];
    #pragma unroll
    for (int m = 0; m < 4; ++m) {
      ga[m] = (f32x4){0.f, 0.f, 0.f, 0.f};
      la[m] = (f32x4){0.f, 0.f, 0.f, 0.f};
    }

    if (k < 100) {
      for (int ks = gks0; ks < gksN; ++ks) {
        bf16x8 b = Gv[((size_t)gntg * 96 + 4 * ks + g) * 16 + c];
        #pragma unroll
        for (int m = 0; m < 4; ++m) {
          bf16x8 a;
          if (ks < 8)   // x-part: A-fragment straight from global x1 (lane-local 16B)
            a = x1v[((size_t)(b0 + m * 16 + c) * T_SZ + k) * 32 + ks * 4 + g];
          else          // h-part from hgst
            a = *(const bf16x8*)&Asm[(m * 16 + c) * 512 + ((((ks - 8) * 4 + g) ^ c7) << 3)];
          ga[m] = MFMA(a, b, ga[m]);
        }
      }
    }
    if (k >= 1) {
      for (int ks = 0; ks < 32; ++ks) {
        bf16x8 b = L2v[((size_t)lntg * 128 + 4 * ks + g) * 16 + c];
        #pragma unroll
        for (int m = 0; m < 4; ++m) {
          bf16x8 a = (ks < 16)
              ? *(const bf16x8*)&Asm[(m * 16 + c) * 512 + (((ks * 4 + g) ^ c7) << 3)]
              : *(const bf16x8*)&Asm[32768 + (m * 16 + c) * 512 + ((((ks - 16) * 4 + g) ^ c7) << 3)];
          la[m] = MFMA(a, b, la[m]);
        }
      }
    }

    // pull h_g[k-1] (hold) before XF buffers overlay hgst
    float hold[4];
    if (k < 100) {
      #pragma unroll
      for (int j = 0; j < 4; ++j) {
        int r = er0 + j;
        hold[j] = bf2f(Asm[r * 512 + (((hcg >> 3) ^ (r & 7)) << 3) + (hcg & 7)]);
      }
    }
    __syncthreads();   // all LDS A reads + hold done -> XF may overlay

    // ---- gate-buffer writes ----
    if (k < 100) {
      #pragma unroll
      for (int m = 0; m < 4; ++m)
        #pragma unroll
        for (int j = 0; j < 4; ++j)
          XFg[(gslot * 64 + m * 16 + 4 * g + j) * 36 + gnt * 16 + c] = ga[m][j];
    }
    if (k >= 1) {
      #pragma unroll
      for (int m = 0; m < 4; ++m)
        #pragma unroll
        for (int j = 0; j < 4; ++j)
          XFl[(lgate * 64 + m * 16 + 4 * g + j) * 36 + ln * 16 + c] = la[m][j];
    }
    __syncthreads();

    // ---- epilogues (slot stride = 64*36 = 2304 floats) ----
    if (k < 100) {
      short* hgw = mode ? hgH + (size_t)(k + 1) * 524288
                        : hg + (size_t)(k & 1) * 524288;
      #pragma unroll
      for (int j = 0; j < 4; ++j) {
        int r = er0 + j;
        int xi = r * 36 + ehc;
        float z  = sigm(XFg[xi] + bz);
        float rr = sigm(XFg[2304 + xi] + br_);
        float hh = tanhf(XFg[4608 + xi] + bxh + rr * (XFg[6912 + xi] + brh));
        float hn = z * hold[j] + (1.f - z) * hh;
        store_short_sys(&hgw[(size_t)(b0 + r) * 512 + hcg], f2bf(hn));
      }
    }
    if (k >= 1) {
      short* hlw = mode ? hlH + (size_t)k * 524288
                        : hl + (size_t)((k + 1) & 1) * 524288;   // h_l[t], t=k-1
      #pragma unroll
      for (int j = 0; j < 4; ++j) {
        int r = er0 + j;
        int xi = r * 36 + ehc;
        float i_ = XFl[xi]        + bi_;
        float f_ = XFl[2304 + xi] + bf_;
        float cc = XFl[4608 + xi] + bc_;
        float o_ = XFl[6912 + xi] + bo_;
        float cn = sigm(f_) * creg[j] + sigm(i_) * tanhf(cc);
        creg[j] = cn;
        float hn = sigm(o_) * tanhf(cn);
        mreg[j] += hn;
        store_short_sys(&hlw[(size_t)(b0 + r) * 512 + hcg], f2bf(hn));
      }
    }

    gbar16(bar, rowwg, k);
  }

  #pragma unroll
  for (int j = 0; j < 4; ++j)
    msum[(size_t)(b0 + er0 + j) * 512 + hcg] = mreg[j];
}

// ---------------- head: mean -> MLP -> softmax/sigmoid ----------------
__global__ __launch_bounds__(256) void head_k(
    const float* __restrict__ msum, const float* __restrict__ upv,
    const float* __restrict__ fc1w, const float* __restrict__ fc1b,
    const float* __restrict__ d1w, const float* __restrict__ d1b,
    const float* __restrict__ d2w, const float* __restrict__ d2b,
    const float* __restrict__ d3w, const float* __restrict__ d3b,
    const float* __restrict__ rw, const float* __restrict__ rb,
    const float* __restrict__ cw, const float* __restrict__ cb,
    float* __restrict__ out) {
  __shared__ float h[1024], o1[64], o2[512], o3[128], lg[8];
  const int b = blockIdx.x, tid = threadIdx.x;
  const float u = upv[b];
  for (int i = tid; i < 512; i += 256) {
    h[i] = msum[b * 512 + i] * 0.01f;
    float v = u * fc1w[i] + fc1b[i];
    h[512 + i] = v > 0.f ? v : 0.f;
  }
  __syncthreads();
  if (tid < 64) {
    float a = d1b[tid];
    for (int i = 0; i < 1024; ++i) a += h[i] * d1w[i * 64 + tid];
    o1[tid] = a > 0.f ? a : 0.f;
  }
  __syncthreads();
  for (int j = tid; j < 512; j += 256) {
    float a = d2b[j];
    for (int i = 0; i < 64; ++i) a += o1[i] * d2w[i * 512 + j];
    o2[j] = a > 0.f ? a : 0.f;
  }
  __syncthreads();
  if (tid < 128) {
    float a = d3b[tid];
    for (int i = 0; i < 512; ++i) a += o2[i] * d3w[i * 128 + tid];
    o3[tid] = a > 0.f ? a : 0.f;
  }
  __syncthreads();
  if (tid < 5) {
    float a = rb[tid];
    for (int i = 0; i < 128; ++i) a += o3[i] * rw[i * 5 + tid];
    lg[tid] = a;
  }
  if (tid == 5) {
    float a = cb[0];
    for (int i = 0; i < 128; ++i) a += o3[i] * cw[i];
    out[5120 + b] = 1.f / (1.f + expf(-a));
  }
  __syncthreads();
  if (tid == 0) {
    float m = lg[0];
    for (int j = 1; j < 5; ++j) m = fmaxf(m, lg[j]);
    float e[5], s = 0.f;
    for (int j = 0; j < 5; ++j) { e[j] = expf(lg[j] - m); s += e[j]; }
    for (int j = 0; j < 5; ++j) out[b * 5 + j] = e[j] / s;
  }
}

// ---------------- launch ----------------
extern "C" void kernel_launch(void* const* d_in, const int* in_sizes, int n_in,
                              void* d_out, int out_size, void* d_ws, size_t ws_size,
                              hipStream_t stream) {
  const int*   text  = (const int*)  d_in[0];
  const float* upv   = (const float*)d_in[1];
  const float* emb   = (const float*)d_in[2];
  const float* gf_k  = (const float*)d_in[3];
  const float* gf_rk = (const float*)d_in[4];
  const float* gf_b  = (const float*)d_in[5];
  const float* lb_k  = (const float*)d_in[6];
  const float* lb_rk = (const float*)d_in[7];
  const float* lb_b  = (const float*)d_in[8];
  const float* g2_k  = (const float*)d_in[9];
  const float* g2_rk = (const float*)d_in[10];
  const float* g2_b  = (const float*)d_in[11];
  const float* l2_k  = (const float*)d_in[12];
  const float* l2_rk = (const float*)d_in[13];
  const float* l2_b  = (const float*)d_in[14];
  const float* fc1_w = (const float*)d_in[15];
  const float* fc1_b = (const float*)d_in[16];
  const float* d1_w  = (const float*)d_in[17];
  const float* d1_b  = (const float*)d_in[18];
  const float* d2_w  = (const float*)d_in[19];
  const float* d2_b  = (const float*)d_in[20];
  const float* d3_w  = (const float*)d_in[21];
  const float* d3_b  = (const float*)d_in[22];
  const float* rat_w = (const float*)d_in[23];
  const float* rat_b = (const float*)d_in[24];
  const float* rec_w = (const float*)d_in[25];
  const float* rec_b = (const float*)d_in[26];

  char* ws = (char*)d_ws;
  short* gfkp  = (short*)(ws + O_GFK);
  short* gfrkp = (short*)(ws + O_GFRK);
  short* lbkp  = (short*)(ws + O_LBK);
  short* lbrkp = (short*)(ws + O_LBRK);
  short* G2p   = (short*)(ws + O_G2);
  short* L2p   = (short*)(ws + O_L2);
  short* xb    = (short*)(ws + O_X);
  short* x1    = (short*)(ws + O_X1);
  short* hg    = (short*)(ws + O_HG);
  short* hl    = (short*)(ws + O_HL);
  unsigned* bar = (unsigned*)(ws + O_BAR);
  float* msum  = (float*)(ws + O_MS);
  short* hgH   = (short*)(ws + O_HGH);
  short* hlH   = (short*)(ws + O_HLH);

  const int mode = (ws_size >= (size_t)WS_NEED) ? 1 : 0;

  pack_b<<<192, 256, 0, stream>>>(gf_k, 100, gf_k, 128, 128, 384, gfkp);
  pack_b<<<192, 256, 0, stream>>>(gf_rk, 128, gf_rk, 128, 128, 384, gfrkp);
  pack_b<<<256, 256, 0, stream>>>(lb_k, 100, lb_k, 128, 128, 512, lbkp);
  pack_b<<<256, 256, 0, stream>>>(lb_rk, 128, lb_rk, 128, 128, 512, lbrkp);
  pack_b<<<4608, 256, 0, stream>>>(g2_k, 256, g2_rk, 256, 768, 1536, G2p);
  pack_b<<<8192, 256, 0, stream>>>(l2_k, 512, l2_rk, 512, 1024, 2048, L2p);

  embed_k<<<51200, 256, 0, stream>>>(text, emb, xb);

  hipMemsetAsync(ws + O_BAR, 0, 4096u, stream);               // barrier counters
  if (mode) {
    hipMemsetAsync(ws + O_HGH, 0, 1048576u, stream);          // hg[-1] = 0
    hipMemsetAsync(ws + O_HLH, 0, 1048576u, stream);          // hl[-1] = 0
  } else {
    hipMemsetAsync(ws + O_HG + 1048576u, 0, 1048576u, stream);
    hipMemsetAsync(ws + O_HL + 1048576u, 0, 1048576u, stream);
  }

  layer1_k<<<128, 512, 0, stream>>>(xb, gfkp, gfrkp, gf_b, lbkp, lbrkp, lb_b, x1);

  {
    const short* x1c = x1; const short* G2c = G2p; const short* L2c = L2p;
    int modec = mode;
    void* kargs[] = {(void*)&x1c, (void*)&G2c, (void*)&g2_b, (void*)&L2c, (void*)&l2_b,
                     (void*)&hg, (void*)&hl, (void*)&hgH, (void*)&hlH,
                     (void*)&msum, (void*)&bar, (void*)&modec};
    hipError_t e = hipLaunchCooperativeKernel((void*)persist2_k, dim3(256), dim3(512),
                                              kargs, 0, stream);
    if (e != hipSuccess) {
      (void)hipGetLastError();  // clear
      persist2_k<<<256, 512, 0, stream>>>(x1c, G2c, g2_b, L2c, l2_b, hg, hl, hgH, hlH,
                                          msum, bar, modec);
    }
  }

  head_k<<<1024, 256, 0, stream>>>(msum, upv, fc1_w, fc1_b, d1_w, d1_b, d2_w, d2_b,
                                   d3_w, d3_b, rat_w, rat_b, rec_w, rec_b,
                                   (float*)d_out);
}